// Round 5
// baseline (188.604 us; speedup 1.0000x reference)
//
#include <hip/hip_runtime.h>

#define NPIX   512
#define NDET   768
#define NSAMP  768
#define NVIEW  360
#define NBATCH 8
#define NDG    (NDET / 32)          // 24 detector groups of 32
#define NITEMS (NDG * NVIEW)        // 8640 blocks

typedef float v2f __attribute__((ext_vector_type(2)));

// u4 dot8: acc += sum_k nib_k(a)*nib_k(b).  Builtin gated in DEVICE pass only
// (R7 lesson: host-pass __has_builtin is false for amdgcn builtins).
__device__ __forceinline__ int udot8(int a, int b, int acc) {
#if defined(__HIP_DEVICE_COMPILE__) && defined(__has_builtin)
#if __has_builtin(__builtin_amdgcn_udot8)
    return (int)__builtin_amdgcn_udot8((unsigned)a, (unsigned)b, (unsigned)acc, false);
#define UDOT8_DONE 1
#endif
#endif
#ifndef UDOT8_DONE
#pragma unroll
    for (int k = 0; k < 8; ++k)
        acc += ((a >> (4 * k)) & 15) * ((b >> (4 * k)) & 15);
    return acc;
#endif
}

// ---------------------------------------------------------------------------
// R21: FORCED packed-fp32 math.  rocprof R20: VALUBusy 93.9% (issue-bound);
// implied dynamic instr/sample (~60-80) is 2-3x the static count (~27) =>
// the v2f ext-vector ops are likely scalarized by ISel (packed-fp32
// selection on CDNA is opportunistic).  These wrappers force v_pk_*_f32 —
// 64-bit VGPR-pair operands, IEEE-identical per component (bit-compatible).
// ---------------------------------------------------------------------------
#if defined(__HIP_DEVICE_COMPILE__)
__device__ __forceinline__ v2f pk_fma(v2f a, v2f b, v2f c) {
    v2f d;
    asm("v_pk_fma_f32 %0, %1, %2, %3" : "=v"(d) : "v"(a), "v"(b), "v"(c));
    return d;
}
__device__ __forceinline__ v2f pk_mul(v2f a, v2f b) {
    v2f d;
    asm("v_pk_mul_f32 %0, %1, %2" : "=v"(d) : "v"(a), "v"(b));
    return d;
}
__device__ __forceinline__ v2f pk_add(v2f a, v2f b) {
    v2f d;
    asm("v_pk_add_f32 %0, %1, %2" : "=v"(d) : "v"(a), "v"(b));
    return d;
}
__device__ __forceinline__ float fract_asm(float x) {
    float d;
    asm("v_fract_f32 %0, %1" : "=v"(d) : "v"(x));   // == x - floor(x)
    return d;
}
#else
__device__ __forceinline__ v2f pk_fma(v2f a, v2f b, v2f c) { return a * b + c; }
__device__ __forceinline__ v2f pk_mul(v2f a, v2f b) { return a * b; }
__device__ __forceinline__ v2f pk_add(v2f a, v2f b) { return a + b; }
__device__ __forceinline__ float fract_asm(float x) { return x - floorf(x); }
#endif

// ---------------------------------------------------------------------------
// R17: dither state carries a -0.5 offset so the pack can use
// v_cvt_pk_u8_f32 (convert + byte-insert in ONE instr).  R15 lesson:
// v_cvt_pk_u8_f32 ROUNDS-to-nearest; round(15w + d - 0.5) == floor(15w + d)
// exactly (ties aside), so with -0.5 folded into the dither state the pk
// path is bit-compatible with the old truncating casts.  Zero-weight
// corners: u = d - 0.5 in [-0.5, 0.5) -> rounds to 0.
// ---------------------------------------------------------------------------
__device__ __forceinline__ int cvt4_u8(float f0, float f1, float f2, float f3) {
#if defined(__HIP_DEVICE_COMPILE__) && defined(__has_builtin)
#if __has_builtin(__builtin_amdgcn_cvt_pk_u8_f32)
    unsigned r;
    r = __builtin_amdgcn_cvt_pk_u8_f32(f0, 0u, 0u);
    r = __builtin_amdgcn_cvt_pk_u8_f32(f1, 1u, r);
    r = __builtin_amdgcn_cvt_pk_u8_f32(f2, 2u, r);
    r = __builtin_amdgcn_cvt_pk_u8_f32(f3, 3u, r);
    return (int)r;
#define CVT4_DONE 1
#endif
#endif
#ifndef CVT4_DONE
    return ((int)(f0 + 0.5f)) | ((int)(f1 + 0.5f) << 8)
         | ((int)(f2 + 0.5f) << 16) | ((int)(f3 + 0.5f) << 24);
#endif
}

__device__ __forceinline__ float fracf(float x) { return x - floorf(x); }

// ---------------------------------------------------------------------------
// Repack image [8,512,512] fp32 -> u4 quad-pack, NIBBLE-INTERLEAVED batches:
//   pixel (y,x), dword d (d=0..3) = batches {2d (even nibbles), 2d+1 (odd)}:
//     nibble 2c   = round(15*v[2d  ]) at corner c
//     nibble 2c+1 = round(15*v[2d+1]) at corner c
//   corners c: 0=(x,y) 1=(x+1,y) 2=(x,y+1) 3=(x+1,y+1)   (clamped)
// ONE dwordx4 gather = all 4 bilinear corners x all 8 batches.
// Footprint 4 MB -> L2-resident (R4 lesson: 8 MB thrashes).
// ---------------------------------------------------------------------------
__global__ __launch_bounds__(256) void repack_kernel(
    const float* __restrict__ image,    // [8, 512, 512]
    int4* __restrict__ packed)          // [512*512]
{
    const int idx = blockIdx.x * blockDim.x + threadIdx.x;  // (y<<9)|x
    if (idx >= NPIX * NPIX) return;
    const int x  = idx & (NPIX - 1);
    const int y  = idx >> 9;
    const int x1 = min(x + 1, NPIX - 1);
    const int y1 = min(y + 1, NPIX - 1);
    const int c0 = (y << 9) + x, c1 = (y << 9) + x1;
    const int c2 = (y1 << 9) + x, c3 = (y1 << 9) + x1;
    int w[4];
#pragma unroll
    for (int d = 0; d < 4; ++d) {
        const float* imgA = image + (size_t)(2 * d)     * (NPIX * NPIX);
        const float* imgB = image + (size_t)(2 * d + 1) * (NPIX * NPIX);
        const int a0 = (int)(imgA[c0] * 15.0f + 0.5f);
        const int a1 = (int)(imgA[c1] * 15.0f + 0.5f);
        const int a2 = (int)(imgA[c2] * 15.0f + 0.5f);
        const int a3 = (int)(imgA[c3] * 15.0f + 0.5f);
        const int b0 = (int)(imgB[c0] * 15.0f + 0.5f);
        const int b1 = (int)(imgB[c1] * 15.0f + 0.5f);
        const int b2 = (int)(imgB[c2] * 15.0f + 0.5f);
        const int b3 = (int)(imgB[c3] * 15.0f + 0.5f);
        w[d] = a0 | (b0 << 4) | (a1 << 8)  | (b1 << 12)
             | (a2 << 16) | (b2 << 20) | (a3 << 24) | (b3 << 28);
    }
    packed[idx] = make_int4(w[0], w[1], w[2], w[3]);
}

// u4 DITHERED weights (8 udot8/sample).  wA: weight[c] in LOW nibble of
// byte c (even-batch nibbles); wA<<4 hits odd-batch nibbles.
// floor(15*w + dither) with shared per-sample dither is UNBIASED for every w
// (R9/R15 lessons: only zero-mean rounding error is tolerable — any constant
// bias accumulates linearly over ~550 samples).
__device__ __forceinline__ void acc_quad_u4(const int4 q, const int wA,
                                            int acc[NBATCH]) {
    const int wB = wA << 4;
    acc[0] = udot8(q.x, wA, acc[0]);
    acc[1] = udot8(q.x, wB, acc[1]);
    acc[2] = udot8(q.y, wA, acc[2]);
    acc[3] = udot8(q.y, wB, acc[3]);
    acc[4] = udot8(q.z, wA, acc[4]);
    acc[5] = udot8(q.z, wB, acc[5]);
    acc[6] = udot8(q.w, wA, acc[6]);
    acc[7] = udot8(q.w, wB, acc[7]);
}

// scalar consume (borders / interior tails).  dith carries the -0.5 offset.
__device__ __forceinline__ void consume(const int4 q, float wx, float wy,
                                        float dith, int acc[NBATCH]) {
    const float ax   = 1.0f - wx;
    const float ay15 = fmaf(wy, -15.0f, 15.0f);
    const float wy15 = wy * 15.0f;
    acc_quad_u4(q, cvt4_u8(fmaf(ax, ay15, dith), fmaf(wx, ay15, dith),
                           fmaf(ax, wy15, dith), fmaf(wx, wy15, dith)), acc);
}

__device__ __forceinline__ int pack_w4d(float w00, float w01, float w10,
                                        float w11, float dith) {
    return cvt4_u8(fmaf(w00, 15.0f, dith), fmaf(w01, 15.0f, dith),
                   fmaf(w10, 15.0f, dith), fmaf(w11, 15.0f, dith));
}

// dither state convention (R17): value = frac(s*phi) - 0.5, in [-0.5, 0.5)
__device__ __forceinline__ float dither_of(float sf) {
    return fracf(sf * 0.61803398875f) - 0.5f;
}

// table index from interior (positive) coords; dead-prefetch safe:
// all arithmetic UNSIGNED (modular, no UB on garbage), then masked in-bounds.
__device__ __forceinline__ unsigned pk_idx_clamped(float fx, float fy) {
    const unsigned ux = (unsigned)(int)fx;
    const unsigned uy = (unsigned)(int)fy;
    return ((uy << 9) + ux) & 0x3FFFFu;
}

// center-out permutation of detector-group rank: 11,12,10,13,9,...,0,23.
// R19: STATIC LPT — item = rank*NVIEW + v, so central (long) fans get the
// lowest blockIdx (launched first) and edge (short/empty) fans drain last.
// Zero runtime overhead; R18's dynamic stealing regressed (barrier lockstep).
__device__ __forceinline__ int dg_center_out(int r) {
    const int off = (r + 1) >> 1;
    return (r & 1) ? (11 + off) : (11 - off);
}

// ---------------------------------------------------------------------------
// Main projector — R21 (= R20 structure + forced v_pk_*_f32 / v_fract_f32
// and re-packed dither update).  Static grid of 8640 blocks (LPT-permuted),
// wave = 8 detectors x 8 sample-offsets.  Per sample: ONE dwordx4 gather +
// 8 v_dot8 (dithered u4 weights).  Interior: 4-SLOT software pipeline
// (A,B,C,D at s,s+8,s+16,s+24; +32/iter) — R20 measured VALUBusy 93.9%, so
// latency is hidden; this round cuts instruction count only.
// Interior addressing: fx,fy in (0,511) guaranteed -> truncating (int) cast
// == floor and v_fract_f32 == fx - floor(fx) BIT-EXACTLY; pk_idx_clamped
// keeps dead last-iteration prefetches in-bounds (loop body branch-free).
// ---------------------------------------------------------------------------
__global__ __launch_bounds__(256) void projector_kernel(
    const int4* __restrict__ pk,        // [512*512] u4 quad-pack interleaved
    const float* __restrict__ views,    // [360]
    float* __restrict__ out)            // [8, 360, 768]
{
    const int lane    = threadIdx.x & 63;
    const int wave    = threadIdx.x >> 6;
    const int detlane = lane & 7;
    const int soff    = lane >> 3;      // 0..7, sample stride 8

    const int item = blockIdx.x;
    const int dgr  = item / NVIEW;          // center-out rank 0..23
    const int v    = item - dgr * NVIEW;    // view 0..359
    const int dg   = dg_center_out(dgr);
    const int d    = dg * 32 + wave * 8 + detlane;

    const float PIX   = 0.7433f;
    const float ISO   = 595.0f;
    const float SDD_  = 595.0f + 490.6f;
    const float DGAM  = 1.2858f / SDD_;
    const float FOV   = 512.0f * 0.7433f * 0.70710678f;
    const float T0    = ISO - FOV;
    const float DT    = 2.0f * FOV / (float)NSAMP;

    const float beta  = views[v];
    const float gamma = ((float)d - 0.5f * (float)(NDET - 1)) * DGAM;
    const float sx = ISO * cosf(beta);
    const float sy = ISO * sinf(beta);
    const float ang = beta + 3.14159265358979f + gamma;
    const float gx = cosf(ang) / PIX;
    const float gy = sinf(ang) / PIX;
    const float cx = sx / PIX + 0.5f * (float)(NPIX - 1);
    const float cy = sy / PIX + 0.5f * (float)(NPIX - 1);

    // ---- clip sample range to image support (contrib 0 outside (-1,512)) --
    const float PLO = -1.0f, PHI = 512.0f;
    float lo = T0 + 0.5f * DT;
    float hi = T0 + ((float)NSAMP - 0.5f) * DT;
    if (fabsf(gx) > 1e-8f) {
        float ta = (PLO - cx) / gx, tb = (PHI - cx) / gx;
        lo = fmaxf(lo, fminf(ta, tb));
        hi = fminf(hi, fmaxf(ta, tb));
    } else if (cx < PLO || cx > PHI) {
        hi = lo - 1.0f;
    }
    if (fabsf(gy) > 1e-8f) {
        float ta = (PLO - cy) / gy, tb = (PHI - cy) / gy;
        lo = fmaxf(lo, fminf(ta, tb));
        hi = fminf(hi, fmaxf(ta, tb));
    } else if (cy < PLO || cy > PHI) {
        hi = lo - 1.0f;
    }

    int s_begin = 0, s_end = 0;
    if (hi >= lo) {
        s_begin = max(0, (int)floorf((lo - T0) / DT - 0.5f));
        s_end   = min(NSAMP, (int)ceilf((hi - T0) / DT - 0.5f) + 1);
    }

    // ---- interior range: strictly inside [0.01, 510.99]^2 (no clamping) ---
    const float XLO = 0.01f, XHI = 510.99f;
    float ilo = lo, ihi = hi;
    if (fabsf(gx) > 1e-8f) {
        float ta = (XLO - cx) / gx, tb = (XHI - cx) / gx;
        ilo = fmaxf(ilo, fminf(ta, tb));
        ihi = fminf(ihi, fmaxf(ta, tb));
    } else if (cx < XLO || cx > XHI) {
        ihi = ilo - 1.0f;
    }
    if (fabsf(gy) > 1e-8f) {
        float ta = (XLO - cy) / gy, tb = (XHI - cy) / gy;
        ilo = fmaxf(ilo, fminf(ta, tb));
        ihi = fminf(ihi, fmaxf(ta, tb));
    } else if (cy < XLO || cy > XHI) {
        ihi = ilo - 1.0f;
    }

    int ib = s_begin, ie = s_begin;
    if (ihi >= ilo) {
        ib = max(s_begin, (int)ceilf ((ilo - T0) / DT - 0.5f));
        ie = min(s_end,   (int)floorf((ihi - T0) / DT - 0.5f) + 1);
        if (ie < ib) { ib = s_begin; ie = s_begin; }
    }

    const float fxs = gx * DT;
    const float fys = gy * DT;
    const float fx0 = fmaf(gx, T0 + 0.5f * DT, cx);
    const float fy0 = fmaf(gy, T0 + 0.5f * DT, cy);

    int acc[NBATCH];
#pragma unroll
    for (int b = 0; b < NBATCH; ++b) acc[b] = 0;

    int s = s_begin + soff;          // this thread's samples: step 8

    // ---------------- border loop 1: s < ib --------------------------------
    for (; s < ib; s += 8) {
        const float sf = (float)s;
        const float fx = fmaf(fxs, sf, fx0);
        const float fy = fmaf(fys, sf, fy0);
        const float x0f = floorf(fx), y0f = floorf(fy);
        const float wx = fx - x0f, wy = fy - y0f;
        const int ix = (int)x0f, iy = (int)y0f;
        const float ax = 1.0f - wx, ay = 1.0f - wy;
        const bool vx0 = (unsigned)ix       < (unsigned)NPIX;
        const bool vx1 = (unsigned)(ix + 1) < (unsigned)NPIX;
        const bool vy0 = (unsigned)iy       < (unsigned)NPIX;
        const bool vy1 = (unsigned)(iy + 1) < (unsigned)NPIX;
        float w00 = (vx0 && vy0) ? ax * ay : 0.0f;
        float w01 = (vx1 && vy0) ? wx * ay : 0.0f;
        float w10 = (vx0 && vy1) ? ax * wy : 0.0f;
        float w11 = (vx1 && vy1) ? wx * wy : 0.0f;
        const bool xneg = (ix < 0);
        float s00 = xneg ? w01 : w00, s01 = xneg ? 0.0f : w01;
        float s10 = xneg ? w11 : w10, s11 = xneg ? 0.0f : w11;
        const bool yneg = (iy < 0);
        const float t00 = yneg ? s10 : s00, t10 = yneg ? 0.0f : s10;
        const float t01 = yneg ? s11 : s01, t11 = yneg ? 0.0f : s11;
        const int px = min(max(ix, 0), NPIX - 1);
        const int py = min(max(iy, 0), NPIX - 1);
        acc_quad_u4(pk[(py << 9) + px],
                    pack_w4d(t00, t01, t10, t11, dither_of(sf)), acc);
    }

    // ---- interior: s < ie, 4-slot software-pipelined, forced pk math ------
    if (s < ie) {
        const int n = (ie - s + 7) >> 3;        // # interior samples
        if (n < 4) {
            for (int j = 0; j < n; ++j) {
                const float sf = (float)(s + 8 * j);
                const float fx = fmaf(fxs, sf, fx0);
                const float fy = fmaf(fys, sf, fy0);
                const float xf = floorf(fx), yf = floorf(fy);
                consume(pk[(int)fmaf(yf, 512.0f, xf)], fx - xf, fy - yf,
                        dither_of(sf), acc);
            }
        } else {
            const int nq = n >> 2, r = n & 3;
            const float sf = (float)s;
            // v2f constants, materialized ONCE (asm operands must be regs)
            v2f c15;   c15.x  = 15.0f;  c15.y  = 15.0f;
            v2f cN15;  cN15.x = -15.0f; cN15.y = -15.0f;
            v2f cONE;  cONE.x = 1.0f;   cONE.y = 1.0f;
            v2f cNEG1; cNEG1.x = -1.0f; cNEG1.y = -1.0f;
            // dither step for stride 32 with the -0.5 state convention:
            // next = fract(state + frac(32*phi) + 0.5) - 0.5;
            // frac(32*phi) = 0.77708764 -> folded additive const 0.27708764
            v2f cDST;  cDST.x = 0.27708764f; cDST.y = 0.27708764f;
            v2f cNH;   cNH.x  = -0.5f;  cNH.y  = -0.5f;
            v2f fxs32; fxs32.x = 32.0f * fxs; fxs32.y = 32.0f * fxs;
            v2f fys32; fys32.x = 32.0f * fys; fys32.y = 32.0f * fys;
            // slot positions: A=s, B=s+8 (vec a), C=s+16, D=s+24 (vec b);
            // each slot advances 32 s-units per iteration.
            v2f fxa, fya, fxb, fyb, d2a, d2b;
            fxa.x = fmaf(fxs, sf, fx0);          fxa.y = fmaf(fxs, sf + 8.0f, fx0);
            fya.x = fmaf(fys, sf, fy0);          fya.y = fmaf(fys, sf + 8.0f, fy0);
            fxb.x = fmaf(fxs, sf + 16.0f, fx0);  fxb.y = fmaf(fxs, sf + 24.0f, fx0);
            fyb.x = fmaf(fys, sf + 16.0f, fy0);  fyb.y = fmaf(fys, sf + 24.0f, fy0);
            d2a.x = dither_of(sf);               d2a.y = dither_of(sf + 8.0f);
            d2b.x = dither_of(sf + 16.0f);       d2b.y = dither_of(sf + 24.0f);
            // prologue loads: all 4 positions genuinely interior (n >= 4 =>
            // ie - s >= 25 => s+24 < ie), so indices are exact & in-bounds.
            int4 qa = pk[pk_idx_clamped(fxa.x, fya.x)];
            int4 qb = pk[pk_idx_clamped(fxa.y, fya.y)];
            int4 qc = pk[pk_idx_clamped(fxb.x, fyb.x)];
            int4 qd = pk[pk_idx_clamped(fxb.y, fyb.y)];
            for (int k = 0; k < nq; ++k) {
                // ---- pair A,B: v_fract (bit-exact interior), forced pk ----
                v2f wxa, wya;
                wxa.x = fract_asm(fxa.x); wxa.y = fract_asm(fxa.y);
                wya.x = fract_asm(fya.x); wya.y = fract_asm(fya.y);
                const v2f axa   = pk_fma(wxa, cNEG1, cONE);   // 1 - wx
                const v2f ay15a = pk_fma(wya, cN15, c15);     // 15 - 15wy
                const v2f wy15a = pk_mul(wya, c15);           // 15wy
                const v2f u0a = pk_fma(axa, ay15a, d2a);
                const v2f u1a = pk_fma(wxa, ay15a, d2a);
                const v2f u2a = pk_fma(axa, wy15a, d2a);
                const v2f u3a = pk_fma(wxa, wy15a, d2a);
                acc_quad_u4(qa, cvt4_u8(u0a.x, u1a.x, u2a.x, u3a.x), acc);
                acc_quad_u4(qb, cvt4_u8(u0a.y, u1a.y, u2a.y, u3a.y), acc);
                fxa = pk_add(fxa, fxs32); fya = pk_add(fya, fys32);
                qa = pk[pk_idx_clamped(fxa.x, fya.x)];
                qb = pk[pk_idx_clamped(fxa.y, fya.y)];
                {   // packed dither update (pk_add + 2 fract + pk_add)
                    v2f t = pk_add(d2a, cDST);
                    v2f f; f.x = fract_asm(t.x); f.y = fract_asm(t.y);
                    d2a = pk_add(f, cNH);
                }
                // ---- pair C,D ----------------------------------------------
                v2f wxb, wyb;
                wxb.x = fract_asm(fxb.x); wxb.y = fract_asm(fxb.y);
                wyb.x = fract_asm(fyb.x); wyb.y = fract_asm(fyb.y);
                const v2f axb   = pk_fma(wxb, cNEG1, cONE);
                const v2f ay15b = pk_fma(wyb, cN15, c15);
                const v2f wy15b = pk_mul(wyb, c15);
                const v2f u0b = pk_fma(axb, ay15b, d2b);
                const v2f u1b = pk_fma(wxb, ay15b, d2b);
                const v2f u2b = pk_fma(axb, wy15b, d2b);
                const v2f u3b = pk_fma(wxb, wy15b, d2b);
                acc_quad_u4(qc, cvt4_u8(u0b.x, u1b.x, u2b.x, u3b.x), acc);
                acc_quad_u4(qd, cvt4_u8(u0b.y, u1b.y, u2b.y, u3b.y), acc);
                fxb = pk_add(fxb, fxs32); fyb = pk_add(fyb, fys32);
                qc = pk[pk_idx_clamped(fxb.x, fyb.x)];
                qd = pk[pk_idx_clamped(fxb.y, fyb.y)];
                {
                    v2f t = pk_add(d2b, cDST);
                    v2f f; f.x = fract_asm(t.x); f.y = fract_asm(t.y);
                    d2b = pk_add(f, cNH);
                }
            }
            // tail r in {0..3}: slots A,B,C hold samples s+32*nq+{0,8,16};
            // those with index < ie (i.e. slot # < r) are genuinely interior,
            // so their clamped reload addresses were exact and the held data
            // is correct.
            if (r > 0) consume(qa, fract_asm(fxa.x), fract_asm(fya.x), d2a.x, acc);
            if (r > 1) consume(qb, fract_asm(fxa.y), fract_asm(fya.y), d2a.y, acc);
            if (r > 2) consume(qc, fract_asm(fxb.x), fract_asm(fyb.x), d2b.x, acc);
        }
        s += n << 3;
    }

    // ---------------- border loop 2: s < s_end -----------------------------
    for (; s < s_end; s += 8) {
        const float sf = (float)s;
        const float fx = fmaf(fxs, sf, fx0);
        const float fy = fmaf(fys, sf, fy0);
        const float x0f = floorf(fx), y0f = floorf(fy);
        const float wx = fx - x0f, wy = fy - y0f;
        const int ix = (int)x0f, iy = (int)y0f;
        const float ax = 1.0f - wx, ay = 1.0f - wy;
        const bool vx0 = (unsigned)ix       < (unsigned)NPIX;
        const bool vx1 = (unsigned)(ix + 1) < (unsigned)NPIX;
        const bool vy0 = (unsigned)iy       < (unsigned)NPIX;
        const bool vy1 = (unsigned)(iy + 1) < (unsigned)NPIX;
        float w00 = (vx0 && vy0) ? ax * ay : 0.0f;
        float w01 = (vx1 && vy0) ? wx * ay : 0.0f;
        float w10 = (vx0 && vy1) ? ax * wy : 0.0f;
        float w11 = (vx1 && vy1) ? wx * wy : 0.0f;
        const bool xneg = (ix < 0);
        float s00 = xneg ? w01 : w00, s01 = xneg ? 0.0f : w01;
        float s10 = xneg ? w11 : w10, s11 = xneg ? 0.0f : w11;
        const bool yneg = (iy < 0);
        const float t00 = yneg ? s10 : s00, t10 = yneg ? 0.0f : s10;
        const float t01 = yneg ? s11 : s01, t11 = yneg ? 0.0f : s11;
        const int px = min(max(ix, 0), NPIX - 1);
        const int py = min(max(iy, 0), NPIX - 1);
        acc_quad_u4(pk[(py << 9) + px],
                    pack_w4d(t00, t01, t10, t11, dither_of(sf)), acc);
    }

    // ---- reduce the 8 soff partials, scale, store -------------------------
#pragma unroll
    for (int b = 0; b < NBATCH; ++b) {
        int a = acc[b];
        a += __shfl_xor(a, 8, 64);
        a += __shfl_xor(a, 16, 64);
        a += __shfl_xor(a, 32, 64);
        acc[b] = a;
    }

    if (soff == 0) {
        const float SCALE = DT * (1.0f / (15.0f * 15.0f));
#pragma unroll
        for (int b = 0; b < NBATCH; ++b)
            out[((size_t)b * NVIEW + v) * NDET + d] = (float)acc[b] * SCALE;
    }
}

// ---------------------------------------------------------------------------
// Fallback (original layout, fp32 scalar loads) — only if ws too small.
// ---------------------------------------------------------------------------
__global__ __launch_bounds__(256) void projector_kernel_fallback(
    const float* __restrict__ image, const float* __restrict__ views,
    float* __restrict__ out)
{
    const int d = blockIdx.x * blockDim.x + threadIdx.x;
    const int v = blockIdx.y;
    if (d >= NDET) return;

    const float PIX = 0.7433f, ISO = 595.0f;
    const float SDD_ = 595.0f + 490.6f;
    const float DGAM = 1.2858f / SDD_;
    const float FOV  = 512.0f * 0.7433f * 0.70710678f;
    const float T0   = ISO - FOV;
    const float DT   = 2.0f * FOV / (float)NSAMP;

    const float beta  = views[v];
    const float gamma = ((float)d - 0.5f * (float)(NDET - 1)) * DGAM;
    const float sx = ISO * cosf(beta), sy = ISO * sinf(beta);
    const float ang = beta + 3.14159265358979f + gamma;
    const float gx = cosf(ang) / PIX, gy = sinf(ang) / PIX;
    const float cx = sx / PIX + 0.5f * (float)(NPIX - 1);
    const float cy = sy / PIX + 0.5f * (float)(NPIX - 1);

    float acc[NBATCH];
#pragma unroll
    for (int b = 0; b < NBATCH; ++b) acc[b] = 0.0f;

    for (int s = 0; s < NSAMP; ++s) {
        const float t  = fmaf((float)s + 0.5f, DT, T0);
        const float fx = fmaf(gx, t, cx);
        const float fy = fmaf(gy, t, cy);
        const float x0f = floorf(fx), y0f = floorf(fy);
        const float wx = fx - x0f, wy = fy - y0f;
        const int ix = (int)x0f, iy = (int)y0f;
        const float ax = 1.0f - wx, ay = 1.0f - wy;
        const bool vx0 = (unsigned)ix < (unsigned)NPIX;
        const bool vx1 = (unsigned)(ix + 1) < (unsigned)NPIX;
        const bool vy0 = (unsigned)iy < (unsigned)NPIX;
        const bool vy1 = (unsigned)(iy + 1) < (unsigned)NPIX;
        const float w00 = (vx0 && vy0) ? ax * ay : 0.0f;
        const float w01 = (vx1 && vy0) ? wx * ay : 0.0f;
        const float w10 = (vx0 && vy1) ? ax * wy : 0.0f;
        const float w11 = (vx1 && vy1) ? wx * wy : 0.0f;
        const int xc0 = min(max(ix, 0), NPIX - 1);
        const int xc1 = min(max(ix + 1, 0), NPIX - 1);
        const int yc0 = min(max(iy, 0), NPIX - 1);
        const int yc1 = min(max(iy + 1, 0), NPIX - 1);
        const int i00 = (yc0 << 9) + xc0, i01 = (yc0 << 9) + xc1;
        const int i10 = (yc1 << 9) + xc0, i11 = (yc1 << 9) + xc1;
#pragma unroll
        for (int b = 0; b < NBATCH; ++b) {
            const float* img = image + (size_t)b * (NPIX * NPIX);
            acc[b] = fmaf(w00, img[i00], fmaf(w01, img[i01],
                     fmaf(w10, img[i10], fmaf(w11, img[i11], acc[b]))));
        }
    }
#pragma unroll
    for (int b = 0; b < NBATCH; ++b)
        out[((size_t)b * NVIEW + v) * NDET + d] = acc[b] * DT;
}

extern "C" void kernel_launch(void* const* d_in, const int* in_sizes, int n_in,
                              void* d_out, int out_size, void* d_ws, size_t ws_size,
                              hipStream_t stream) {
    const float* image = (const float*)d_in[0];
    const float* views = (const float*)d_in[1];
    float* out = (float*)d_out;

    const size_t packed_bytes = (size_t)NPIX * NPIX * sizeof(int4);
    if (ws_size >= packed_bytes && d_ws != nullptr) {
        int4* packed = (int4*)d_ws;
        repack_kernel<<<dim3((NPIX * NPIX) / 256), dim3(256), 0, stream>>>(image, packed);
        projector_kernel<<<dim3(NITEMS), dim3(256), 0, stream>>>(packed, views, out);
    } else {
        projector_kernel_fallback<<<dim3(NDET / 256, NVIEW), dim3(256), 0, stream>>>(image, views, out);
    }
}

// Round 6
// 181.490 us; speedup vs baseline: 1.0392x; 1.0392x over previous
//
#include <hip/hip_runtime.h>

#define NPIX   512
#define NDET   768
#define NSAMP  768
#define NVIEW  360
#define NBATCH 8
#define NDG    (NDET / 16)          // R22: 48 detector groups of 16
#define NITEMS (NDG * NVIEW)        // 17280 blocks (128 thr = 2 waves each)

typedef float v2f __attribute__((ext_vector_type(2)));

// u4 dot8: acc += sum_k nib_k(a)*nib_k(b).  Builtin gated in DEVICE pass only
// (R7 lesson: host-pass __has_builtin is false for amdgcn builtins).
__device__ __forceinline__ int udot8(int a, int b, int acc) {
#if defined(__HIP_DEVICE_COMPILE__) && defined(__has_builtin)
#if __has_builtin(__builtin_amdgcn_udot8)
    return (int)__builtin_amdgcn_udot8((unsigned)a, (unsigned)b, (unsigned)acc, false);
#define UDOT8_DONE 1
#endif
#endif
#ifndef UDOT8_DONE
#pragma unroll
    for (int k = 0; k < 8; ++k)
        acc += ((a >> (4 * k)) & 15) * ((b >> (4 * k)) & 15);
    return acc;
#endif
}

// ---------------------------------------------------------------------------
// R17: dither state carries a -0.5 offset so the pack can use
// v_cvt_pk_u8_f32 (convert + byte-insert in ONE instr).  R15 lesson:
// v_cvt_pk_u8_f32 ROUNDS-to-nearest; round(15w + d - 0.5) == floor(15w + d)
// exactly (ties aside), so with -0.5 folded into the dither state the pk
// path is bit-compatible with the old truncating casts.  Zero-weight
// corners: u = d - 0.5 in [-0.5, 0.5) -> rounds to 0.
// R21 lesson: do NOT replace the v2f ext-vector math with forced inline-asm
// v_pk_* — the compiler's native codegen is better (asm fences scheduling,
// forces constants into VGPRs; measured -6%).
// ---------------------------------------------------------------------------
__device__ __forceinline__ int cvt4_u8(float f0, float f1, float f2, float f3) {
#if defined(__HIP_DEVICE_COMPILE__) && defined(__has_builtin)
#if __has_builtin(__builtin_amdgcn_cvt_pk_u8_f32)
    unsigned r;
    r = __builtin_amdgcn_cvt_pk_u8_f32(f0, 0u, 0u);
    r = __builtin_amdgcn_cvt_pk_u8_f32(f1, 1u, r);
    r = __builtin_amdgcn_cvt_pk_u8_f32(f2, 2u, r);
    r = __builtin_amdgcn_cvt_pk_u8_f32(f3, 3u, r);
    return (int)r;
#define CVT4_DONE 1
#endif
#endif
#ifndef CVT4_DONE
    return ((int)(f0 + 0.5f)) | ((int)(f1 + 0.5f) << 8)
         | ((int)(f2 + 0.5f) << 16) | ((int)(f3 + 0.5f) << 24);
#endif
}

__device__ __forceinline__ float fract1(float x) {
#if defined(__HIP_DEVICE_COMPILE__) && defined(__has_builtin)
#if __has_builtin(__builtin_amdgcn_fractf)
    return __builtin_amdgcn_fractf(x);      // v_fract_f32 == x - floor(x)
#define FRACT_DONE 1
#endif
#endif
#ifndef FRACT_DONE
    return x - floorf(x);
#endif
}

__device__ __forceinline__ float fracf(float x) { return x - floorf(x); }

// ---------------------------------------------------------------------------
// Repack image [8,512,512] fp32 -> u4 quad-pack, NIBBLE-INTERLEAVED batches:
//   pixel (y,x), dword d (d=0..3) = batches {2d (even nibbles), 2d+1 (odd)}:
//     nibble 2c   = round(15*v[2d  ]) at corner c
//     nibble 2c+1 = round(15*v[2d+1]) at corner c
//   corners c: 0=(x,y) 1=(x+1,y) 2=(x,y+1) 3=(x+1,y+1)   (clamped)
// ONE dwordx4 gather = all 4 bilinear corners x all 8 batches.
// Footprint 4 MB -> L2-resident (R4 lesson: 8 MB thrashes).
// ---------------------------------------------------------------------------
__global__ __launch_bounds__(256) void repack_kernel(
    const float* __restrict__ image,    // [8, 512, 512]
    int4* __restrict__ packed)          // [512*512]
{
    const int idx = blockIdx.x * blockDim.x + threadIdx.x;  // (y<<9)|x
    if (idx >= NPIX * NPIX) return;
    const int x  = idx & (NPIX - 1);
    const int y  = idx >> 9;
    const int x1 = min(x + 1, NPIX - 1);
    const int y1 = min(y + 1, NPIX - 1);
    const int c0 = (y << 9) + x, c1 = (y << 9) + x1;
    const int c2 = (y1 << 9) + x, c3 = (y1 << 9) + x1;
    int w[4];
#pragma unroll
    for (int d = 0; d < 4; ++d) {
        const float* imgA = image + (size_t)(2 * d)     * (NPIX * NPIX);
        const float* imgB = image + (size_t)(2 * d + 1) * (NPIX * NPIX);
        const int a0 = (int)(imgA[c0] * 15.0f + 0.5f);
        const int a1 = (int)(imgA[c1] * 15.0f + 0.5f);
        const int a2 = (int)(imgA[c2] * 15.0f + 0.5f);
        const int a3 = (int)(imgA[c3] * 15.0f + 0.5f);
        const int b0 = (int)(imgB[c0] * 15.0f + 0.5f);
        const int b1 = (int)(imgB[c1] * 15.0f + 0.5f);
        const int b2 = (int)(imgB[c2] * 15.0f + 0.5f);
        const int b3 = (int)(imgB[c3] * 15.0f + 0.5f);
        w[d] = a0 | (b0 << 4) | (a1 << 8)  | (b1 << 12)
             | (a2 << 16) | (b2 << 20) | (a3 << 24) | (b3 << 28);
    }
    packed[idx] = make_int4(w[0], w[1], w[2], w[3]);
}

// u4 DITHERED weights (8 udot8/sample).  wA: weight[c] in LOW nibble of
// byte c (even-batch nibbles); wA<<4 hits odd-batch nibbles.
// floor(15*w + dither) with shared per-sample dither is UNBIASED for every w
// (R9/R15 lessons: only zero-mean rounding error is tolerable — any constant
// bias accumulates linearly over ~550 samples).
__device__ __forceinline__ void acc_quad_u4(const int4 q, const int wA,
                                            int acc[NBATCH]) {
    const int wB = wA << 4;
    acc[0] = udot8(q.x, wA, acc[0]);
    acc[1] = udot8(q.x, wB, acc[1]);
    acc[2] = udot8(q.y, wA, acc[2]);
    acc[3] = udot8(q.y, wB, acc[3]);
    acc[4] = udot8(q.z, wA, acc[4]);
    acc[5] = udot8(q.z, wB, acc[5]);
    acc[6] = udot8(q.w, wA, acc[6]);
    acc[7] = udot8(q.w, wB, acc[7]);
}

// scalar consume (borders / interior tails).  dith carries the -0.5 offset.
__device__ __forceinline__ void consume(const int4 q, float wx, float wy,
                                        float dith, int acc[NBATCH]) {
    const float ax   = 1.0f - wx;
    const float ay15 = fmaf(wy, -15.0f, 15.0f);
    const float wy15 = wy * 15.0f;
    acc_quad_u4(q, cvt4_u8(fmaf(ax, ay15, dith), fmaf(wx, ay15, dith),
                           fmaf(ax, wy15, dith), fmaf(wx, wy15, dith)), acc);
}

__device__ __forceinline__ int pack_w4d(float w00, float w01, float w10,
                                        float w11, float dith) {
    return cvt4_u8(fmaf(w00, 15.0f, dith), fmaf(w01, 15.0f, dith),
                   fmaf(w10, 15.0f, dith), fmaf(w11, 15.0f, dith));
}

// dither state convention (R17): value = frac(s*phi) - 0.5, in [-0.5, 0.5)
__device__ __forceinline__ float dither_of(float sf) {
    return fracf(sf * 0.61803398875f) - 0.5f;
}

// table index from interior (positive) coords; dead-prefetch safe:
// all arithmetic UNSIGNED (modular, no UB on garbage), then masked in-bounds.
__device__ __forceinline__ unsigned pk_idx_clamped(float fx, float fy) {
    const unsigned ux = (unsigned)(int)fx;
    const unsigned uy = (unsigned)(int)fy;
    return ((uy << 9) + ux) & 0x3FFFFu;
}

// center-out permutation of detector-group rank, NDG=48: 23,24,22,25,...,0,47.
// STATIC LPT — central (long) fans get the lowest blockIdx (launched first),
// edge (short/empty) fans drain last.  (R18's dynamic stealing regressed.)
__device__ __forceinline__ int dg_center_out(int r) {
    const int off = (r + 1) >> 1;
    return (r & 1) ? (23 + off) : (23 - off + ((r & 1) ? 0 : (r ? 0 : 0)));
}

// ---------------------------------------------------------------------------
// Main projector — R22 (= R20 math, 128-thread blocks).  rocprof R20/R21:
// VALUBusy 94% (issue-bound), occupancy 60% = drain-tail granularity.  R22
// halves the scheduling quantum: 2-wave blocks over 16-det groups (17280
// blocks).  Wave structure (8 det x 8 soff) UNCHANGED -> every thread's
// arithmetic is bit-identical to R20; only block partitioning changes.
// Per sample: ONE dwordx4 gather + 8 v_dot8 (dithered u4 weights).
// Interior: 4-SLOT software pipeline (A,B,C,D at s,s+8,s+16,s+24; +32/iter)
// — gather latency fully covered (R20: VALUBusy 93.9%).
// Interior addressing: fx,fy in (0,511) guaranteed -> truncating (int) cast
// == floor and v_fract_f32 == fx - floor(fx) BIT-EXACTLY; pk_idx_clamped
// keeps dead last-iteration prefetches in-bounds (loop body branch-free).
// R21 lesson: leave codegen to the compiler — no inline-asm in this loop.
// ---------------------------------------------------------------------------
__global__ __launch_bounds__(128) void projector_kernel(
    const int4* __restrict__ pk,        // [512*512] u4 quad-pack interleaved
    const float* __restrict__ views,    // [360]
    float* __restrict__ out)            // [8, 360, 768]
{
    const int lane    = threadIdx.x & 63;
    const int wave    = threadIdx.x >> 6;   // 0..1
    const int detlane = lane & 7;
    const int soff    = lane >> 3;      // 0..7, sample stride 8

    const int item = blockIdx.x;
    const int dgr  = item / NVIEW;          // center-out rank 0..47
    const int v    = item - dgr * NVIEW;    // view 0..359
    const int dg   = dg_center_out(dgr);
    const int d    = dg * 16 + wave * 8 + detlane;

    const float PIX   = 0.7433f;
    const float ISO   = 595.0f;
    const float SDD_  = 595.0f + 490.6f;
    const float DGAM  = 1.2858f / SDD_;
    const float FOV   = 512.0f * 0.7433f * 0.70710678f;
    const float T0    = ISO - FOV;
    const float DT    = 2.0f * FOV / (float)NSAMP;

    const float beta  = views[v];
    const float gamma = ((float)d - 0.5f * (float)(NDET - 1)) * DGAM;
    const float sx = ISO * cosf(beta);
    const float sy = ISO * sinf(beta);
    const float ang = beta + 3.14159265358979f + gamma;
    const float gx = cosf(ang) / PIX;
    const float gy = sinf(ang) / PIX;
    const float cx = sx / PIX + 0.5f * (float)(NPIX - 1);
    const float cy = sy / PIX + 0.5f * (float)(NPIX - 1);

    // ---- clip sample range to image support (contrib 0 outside (-1,512)) --
    const float PLO = -1.0f, PHI = 512.0f;
    float lo = T0 + 0.5f * DT;
    float hi = T0 + ((float)NSAMP - 0.5f) * DT;
    if (fabsf(gx) > 1e-8f) {
        float ta = (PLO - cx) / gx, tb = (PHI - cx) / gx;
        lo = fmaxf(lo, fminf(ta, tb));
        hi = fminf(hi, fmaxf(ta, tb));
    } else if (cx < PLO || cx > PHI) {
        hi = lo - 1.0f;
    }
    if (fabsf(gy) > 1e-8f) {
        float ta = (PLO - cy) / gy, tb = (PHI - cy) / gy;
        lo = fmaxf(lo, fminf(ta, tb));
        hi = fminf(hi, fmaxf(ta, tb));
    } else if (cy < PLO || cy > PHI) {
        hi = lo - 1.0f;
    }

    int s_begin = 0, s_end = 0;
    if (hi >= lo) {
        s_begin = max(0, (int)floorf((lo - T0) / DT - 0.5f));
        s_end   = min(NSAMP, (int)ceilf((hi - T0) / DT - 0.5f) + 1);
    }

    // ---- interior range: strictly inside [0.01, 510.99]^2 (no clamping) ---
    const float XLO = 0.01f, XHI = 510.99f;
    float ilo = lo, ihi = hi;
    if (fabsf(gx) > 1e-8f) {
        float ta = (XLO - cx) / gx, tb = (XHI - cx) / gx;
        ilo = fmaxf(ilo, fminf(ta, tb));
        ihi = fminf(ihi, fmaxf(ta, tb));
    } else if (cx < XLO || cx > XHI) {
        ihi = ilo - 1.0f;
    }
    if (fabsf(gy) > 1e-8f) {
        float ta = (XLO - cy) / gy, tb = (XHI - cy) / gy;
        ilo = fmaxf(ilo, fminf(ta, tb));
        ihi = fminf(ihi, fmaxf(ta, tb));
    } else if (cy < XLO || cy > XHI) {
        ihi = ilo - 1.0f;
    }

    int ib = s_begin, ie = s_begin;
    if (ihi >= ilo) {
        ib = max(s_begin, (int)ceilf ((ilo - T0) / DT - 0.5f));
        ie = min(s_end,   (int)floorf((ihi - T0) / DT - 0.5f) + 1);
        if (ie < ib) { ib = s_begin; ie = s_begin; }
    }

    const float fxs = gx * DT;
    const float fys = gy * DT;
    const float fx0 = fmaf(gx, T0 + 0.5f * DT, cx);
    const float fy0 = fmaf(gy, T0 + 0.5f * DT, cy);

    int acc[NBATCH];
#pragma unroll
    for (int b = 0; b < NBATCH; ++b) acc[b] = 0;

    int s = s_begin + soff;          // this thread's samples: step 8

    // ---------------- border loop 1: s < ib --------------------------------
    for (; s < ib; s += 8) {
        const float sf = (float)s;
        const float fx = fmaf(fxs, sf, fx0);
        const float fy = fmaf(fys, sf, fy0);
        const float x0f = floorf(fx), y0f = floorf(fy);
        const float wx = fx - x0f, wy = fy - y0f;
        const int ix = (int)x0f, iy = (int)y0f;
        const float ax = 1.0f - wx, ay = 1.0f - wy;
        const bool vx0 = (unsigned)ix       < (unsigned)NPIX;
        const bool vx1 = (unsigned)(ix + 1) < (unsigned)NPIX;
        const bool vy0 = (unsigned)iy       < (unsigned)NPIX;
        const bool vy1 = (unsigned)(iy + 1) < (unsigned)NPIX;
        float w00 = (vx0 && vy0) ? ax * ay : 0.0f;
        float w01 = (vx1 && vy0) ? wx * ay : 0.0f;
        float w10 = (vx0 && vy1) ? ax * wy : 0.0f;
        float w11 = (vx1 && vy1) ? wx * wy : 0.0f;
        const bool xneg = (ix < 0);
        float s00 = xneg ? w01 : w00, s01 = xneg ? 0.0f : w01;
        float s10 = xneg ? w11 : w10, s11 = xneg ? 0.0f : w11;
        const bool yneg = (iy < 0);
        const float t00 = yneg ? s10 : s00, t10 = yneg ? 0.0f : s10;
        const float t01 = yneg ? s11 : s01, t11 = yneg ? 0.0f : s11;
        const int px = min(max(ix, 0), NPIX - 1);
        const int py = min(max(iy, 0), NPIX - 1);
        acc_quad_u4(pk[(py << 9) + px],
                    pack_w4d(t00, t01, t10, t11, dither_of(sf)), acc);
    }

    // ---- interior: s < ie, 4-slot software-pipelined ----------------------
    if (s < ie) {
        const int n = (ie - s + 7) >> 3;        // # interior samples
        if (n < 4) {
            for (int j = 0; j < n; ++j) {
                const float sf = (float)(s + 8 * j);
                const float fx = fmaf(fxs, sf, fx0);
                const float fy = fmaf(fys, sf, fy0);
                const float xf = floorf(fx), yf = floorf(fy);
                consume(pk[(int)fmaf(yf, 512.0f, xf)], fx - xf, fy - yf,
                        dither_of(sf), acc);
            }
        } else {
            const int nq = n >> 2, r = n & 3;
            const float sf = (float)s;
            // slot positions: A=s, B=s+8 (vec a), C=s+16, D=s+24 (vec b);
            // each slot advances 32 s-units per iteration.
            v2f fxs32; fxs32.x = 32.0f * fxs; fxs32.y = 32.0f * fxs;
            v2f fys32; fys32.x = 32.0f * fys; fys32.y = 32.0f * fys;
            // dither step for stride 32 with the -0.5 state convention:
            // next = fract(state + frac(32*phi) + 0.5) - 0.5;
            // frac(32*phi) = 0.77708764 -> folded additive const 0.27708764
            const float DST = 0.27708764f;
            v2f fxa, fya, fxb, fyb, d2a, d2b;
            fxa.x = fmaf(fxs, sf, fx0);          fxa.y = fmaf(fxs, sf + 8.0f, fx0);
            fya.x = fmaf(fys, sf, fy0);          fya.y = fmaf(fys, sf + 8.0f, fy0);
            fxb.x = fmaf(fxs, sf + 16.0f, fx0);  fxb.y = fmaf(fxs, sf + 24.0f, fx0);
            fyb.x = fmaf(fys, sf + 16.0f, fy0);  fyb.y = fmaf(fys, sf + 24.0f, fy0);
            d2a.x = dither_of(sf);               d2a.y = dither_of(sf + 8.0f);
            d2b.x = dither_of(sf + 16.0f);       d2b.y = dither_of(sf + 24.0f);
            // prologue loads: all 4 positions genuinely interior (n >= 4 =>
            // ie - s >= 25 => s+24 < ie), so indices are exact & in-bounds.
            int4 qa = pk[pk_idx_clamped(fxa.x, fya.x)];
            int4 qb = pk[pk_idx_clamped(fxa.y, fya.y)];
            int4 qc = pk[pk_idx_clamped(fxb.x, fyb.x)];
            int4 qd = pk[pk_idx_clamped(fxb.y, fyb.y)];
            for (int k = 0; k < nq; ++k) {
                // ---- pair A,B: weights (v_fract == fx - floor, bit-exact),
                //      consume, then immediately reload for next iteration --
                v2f wxa; wxa.x = fract1(fxa.x); wxa.y = fract1(fxa.y);
                v2f wya; wya.x = fract1(fya.x); wya.y = fract1(fya.y);
                const v2f axa   = 1.0f - wxa;
                const v2f ay15a = wya * -15.0f + 15.0f;
                const v2f wy15a = wya * 15.0f;
                const v2f u0a = axa * ay15a + d2a;
                const v2f u1a = wxa * ay15a + d2a;
                const v2f u2a = axa * wy15a + d2a;
                const v2f u3a = wxa * wy15a + d2a;
                acc_quad_u4(qa, cvt4_u8(u0a.x, u1a.x, u2a.x, u3a.x), acc);
                acc_quad_u4(qb, cvt4_u8(u0a.y, u1a.y, u2a.y, u3a.y), acc);
                fxa += fxs32; fya += fys32;
                qa = pk[pk_idx_clamped(fxa.x, fya.x)];
                qb = pk[pk_idx_clamped(fxa.y, fya.y)];
                d2a.x = fract1(d2a.x + DST) - 0.5f;
                d2a.y = fract1(d2a.y + DST) - 0.5f;
                // ---- pair C,D ----------------------------------------------
                v2f wxb; wxb.x = fract1(fxb.x); wxb.y = fract1(fxb.y);
                v2f wyb; wyb.x = fract1(fyb.x); wyb.y = fract1(fyb.y);
                const v2f axb   = 1.0f - wxb;
                const v2f ay15b = wyb * -15.0f + 15.0f;
                const v2f wy15b = wyb * 15.0f;
                const v2f u0b = axb * ay15b + d2b;
                const v2f u1b = wxb * ay15b + d2b;
                const v2f u2b = axb * wy15b + d2b;
                const v2f u3b = wxb * wy15b + d2b;
                acc_quad_u4(qc, cvt4_u8(u0b.x, u1b.x, u2b.x, u3b.x), acc);
                acc_quad_u4(qd, cvt4_u8(u0b.y, u1b.y, u2b.y, u3b.y), acc);
                fxb += fxs32; fyb += fys32;
                qc = pk[pk_idx_clamped(fxb.x, fyb.x)];
                qd = pk[pk_idx_clamped(fxb.y, fyb.y)];
                d2b.x = fract1(d2b.x + DST) - 0.5f;
                d2b.y = fract1(d2b.y + DST) - 0.5f;
            }
            // tail r in {0..3}: slots A,B,C hold samples s+32*nq+{0,8,16};
            // those with index < ie (i.e. slot # < r) are genuinely interior,
            // so their clamped reload addresses were exact and the held data
            // is correct.
            if (r > 0) consume(qa, fract1(fxa.x), fract1(fya.x), d2a.x, acc);
            if (r > 1) consume(qb, fract1(fxa.y), fract1(fya.y), d2a.y, acc);
            if (r > 2) consume(qc, fract1(fxb.x), fract1(fyb.x), d2b.x, acc);
        }
        s += n << 3;
    }

    // ---------------- border loop 2: s < s_end -----------------------------
    for (; s < s_end; s += 8) {
        const float sf = (float)s;
        const float fx = fmaf(fxs, sf, fx0);
        const float fy = fmaf(fys, sf, fy0);
        const float x0f = floorf(fx), y0f = floorf(fy);
        const float wx = fx - x0f, wy = fy - y0f;
        const int ix = (int)x0f, iy = (int)y0f;
        const float ax = 1.0f - wx, ay = 1.0f - wy;
        const bool vx0 = (unsigned)ix       < (unsigned)NPIX;
        const bool vx1 = (unsigned)(ix + 1) < (unsigned)NPIX;
        const bool vy0 = (unsigned)iy       < (unsigned)NPIX;
        const bool vy1 = (unsigned)(iy + 1) < (unsigned)NPIX;
        float w00 = (vx0 && vy0) ? ax * ay : 0.0f;
        float w01 = (vx1 && vy0) ? wx * ay : 0.0f;
        float w10 = (vx0 && vy1) ? ax * wy : 0.0f;
        float w11 = (vx1 && vy1) ? wx * wy : 0.0f;
        const bool xneg = (ix < 0);
        float s00 = xneg ? w01 : w00, s01 = xneg ? 0.0f : w01;
        float s10 = xneg ? w11 : w10, s11 = xneg ? 0.0f : w11;
        const bool yneg = (iy < 0);
        const float t00 = yneg ? s10 : s00, t10 = yneg ? 0.0f : s10;
        const float t01 = yneg ? s11 : s01, t11 = yneg ? 0.0f : s11;
        const int px = min(max(ix, 0), NPIX - 1);
        const int py = min(max(iy, 0), NPIX - 1);
        acc_quad_u4(pk[(py << 9) + px],
                    pack_w4d(t00, t01, t10, t11, dither_of(sf)), acc);
    }

    // ---- reduce the 8 soff partials, scale, store -------------------------
#pragma unroll
    for (int b = 0; b < NBATCH; ++b) {
        int a = acc[b];
        a += __shfl_xor(a, 8, 64);
        a += __shfl_xor(a, 16, 64);
        a += __shfl_xor(a, 32, 64);
        acc[b] = a;
    }

    if (soff == 0) {
        const float SCALE = DT * (1.0f / (15.0f * 15.0f));
#pragma unroll
        for (int b = 0; b < NBATCH; ++b)
            out[((size_t)b * NVIEW + v) * NDET + d] = (float)acc[b] * SCALE;
    }
}

// ---------------------------------------------------------------------------
// Fallback (original layout, fp32 scalar loads) — only if ws too small.
// ---------------------------------------------------------------------------
__global__ __launch_bounds__(256) void projector_kernel_fallback(
    const float* __restrict__ image, const float* __restrict__ views,
    float* __restrict__ out)
{
    const int d = blockIdx.x * blockDim.x + threadIdx.x;
    const int v = blockIdx.y;
    if (d >= NDET) return;

    const float PIX = 0.7433f, ISO = 595.0f;
    const float SDD_ = 595.0f + 490.6f;
    const float DGAM = 1.2858f / SDD_;
    const float FOV  = 512.0f * 0.7433f * 0.70710678f;
    const float T0   = ISO - FOV;
    const float DT   = 2.0f * FOV / (float)NSAMP;

    const float beta  = views[v];
    const float gamma = ((float)d - 0.5f * (float)(NDET - 1)) * DGAM;
    const float sx = ISO * cosf(beta), sy = ISO * sinf(beta);
    const float ang = beta + 3.14159265358979f + gamma;
    const float gx = cosf(ang) / PIX, gy = sinf(ang) / PIX;
    const float cx = sx / PIX + 0.5f * (float)(NPIX - 1);
    const float cy = sy / PIX + 0.5f * (float)(NPIX - 1);

    float acc[NBATCH];
#pragma unroll
    for (int b = 0; b < NBATCH; ++b) acc[b] = 0.0f;

    for (int s = 0; s < NSAMP; ++s) {
        const float t  = fmaf((float)s + 0.5f, DT, T0);
        const float fx = fmaf(gx, t, cx);
        const float fy = fmaf(gy, t, cy);
        const float x0f = floorf(fx), y0f = floorf(fy);
        const float wx = fx - x0f, wy = fy - y0f;
        const int ix = (int)x0f, iy = (int)y0f;
        const float ax = 1.0f - wx, ay = 1.0f - wy;
        const bool vx0 = (unsigned)ix < (unsigned)NPIX;
        const bool vx1 = (unsigned)(ix + 1) < (unsigned)NPIX;
        const bool vy0 = (unsigned)iy < (unsigned)NPIX;
        const bool vy1 = (unsigned)(iy + 1) < (unsigned)NPIX;
        const float w00 = (vx0 && vy0) ? ax * ay : 0.0f;
        const float w01 = (vx1 && vy0) ? wx * ay : 0.0f;
        const float w10 = (vx0 && vy1) ? ax * wy : 0.0f;
        const float w11 = (vx1 && vy1) ? wx * wy : 0.0f;
        const int xc0 = min(max(ix, 0), NPIX - 1);
        const int xc1 = min(max(ix + 1, 0), NPIX - 1);
        const int yc0 = min(max(iy, 0), NPIX - 1);
        const int yc1 = min(max(iy + 1, 0), NPIX - 1);
        const int i00 = (yc0 << 9) + xc0, i01 = (yc0 << 9) + xc1;
        const int i10 = (yc1 << 9) + xc0, i11 = (yc1 << 9) + xc1;
#pragma unroll
        for (int b = 0; b < NBATCH; ++b) {
            const float* img = image + (size_t)b * (NPIX * NPIX);
            acc[b] = fmaf(w00, img[i00], fmaf(w01, img[i01],
                     fmaf(w10, img[i10], fmaf(w11, img[i11], acc[b]))));
        }
    }
#pragma unroll
    for (int b = 0; b < NBATCH; ++b)
        out[((size_t)b * NVIEW + v) * NDET + d] = acc[b] * DT;
}

extern "C" void kernel_launch(void* const* d_in, const int* in_sizes, int n_in,
                              void* d_out, int out_size, void* d_ws, size_t ws_size,
                              hipStream_t stream) {
    const float* image = (const float*)d_in[0];
    const float* views = (const float*)d_in[1];
    float* out = (float*)d_out;

    const size_t packed_bytes = (size_t)NPIX * NPIX * sizeof(int4);
    if (ws_size >= packed_bytes && d_ws != nullptr) {
        int4* packed = (int4*)d_ws;
        repack_kernel<<<dim3((NPIX * NPIX) / 256), dim3(256), 0, stream>>>(image, packed);
        projector_kernel<<<dim3(NITEMS), dim3(128), 0, stream>>>(packed, views, out);
    } else {
        projector_kernel_fallback<<<dim3(NDET / 256, NVIEW), dim3(256), 0, stream>>>(image, views, out);
    }
}